// Round 9
// baseline (169.370 us; speedup 1.0000x reference)
//
#include <hip/hip_runtime.h>

#define B_ 2
#define D_ 1024
#define T_ 2048
#define H_ 16
#define DH_ 64
#define BH_ (B_ * H_)

typedef __attribute__((ext_vector_type(8))) short bf16x8;
typedef __attribute__((ext_vector_type(8))) unsigned short u16x8;
typedef __attribute__((ext_vector_type(4))) float f32x4;

// two f32 -> packed 2x bf16 (RNE) in ONE VALU op (no builtin on gfx950; T12 recipe)
__device__ __forceinline__ unsigned cvt_pk_bf16(float a, float b) {
    unsigned r;
    asm("v_cvt_pk_bf16_f32 %0, %1, %2" : "=v"(r) : "v"(a), "v"(b));
    return r;
}

// async global->LDS, 16 B per lane: LDS dest is wave-uniform base + lane*16,
// global src is per-lane.  (m97 pattern; size must be a literal.)
__device__ __forceinline__ void gload_lds16(const unsigned short* g, unsigned short* l) {
    __builtin_amdgcn_global_load_lds(
        (const __attribute__((address_space(1))) unsigned int*)(const void*)g,
        (__attribute__((address_space(3))) unsigned int*)(void*)l,
        16, 0, 0);
}

// ---------------------------------------------------------------------------
// Kernel T1: x (B,D,T) fp32 -> xT (B,T,D) bf16.  64x64 tiles through LDS.
// ---------------------------------------------------------------------------
__global__ __launch_bounds__(256) void xpose_kernel(
    const float* __restrict__ x, unsigned short* __restrict__ xT)
{
    __shared__ __align__(16) unsigned short Ls[64][68];
    const int t0 = blockIdx.x * 64;
    const int d0 = blockIdx.y * 64;
    const int b  = blockIdx.z;
    const int tid = threadIdx.x;

    const float* xb = x + (size_t)b * D_ * T_ + (size_t)d0 * T_ + t0;
    #pragma unroll
    for (int p = 0; p < 4; p++) {
        int i4  = tid + p * 256;
        int row = i4 >> 4;            // d
        int c4  = (i4 & 15) << 2;     // t
        float4 v = *(const float4*)(xb + (size_t)row * T_ + c4);
        uint2 u;
        u.x = cvt_pk_bf16(v.x, v.y);
        u.y = cvt_pk_bf16(v.z, v.w);
        *(uint2*)&Ls[row][c4] = u;
    }
    __syncthreads();
    unsigned short* ob = xT + (size_t)b * T_ * D_ + (size_t)t0 * D_ + d0;
    #pragma unroll
    for (int p = 0; p < 2; p++) {
        int i    = tid + p * 256;
        int orow = i >> 3;            // t
        int oc8  = (i & 7) * 8;       // d
        u16x8 tv;
        #pragma unroll
        for (int j = 0; j < 8; j++) tv[j] = Ls[oc8 + j][orow];
        *(u16x8*)(ob + (size_t)orow * D_ + oc8) = tv;
    }
}

// ---------------------------------------------------------------------------
// Kernel T2: w (3,H,D,Dh) fp32 -> wT (3,H,Dh,D) bf16.  64x64 tiles.
// ---------------------------------------------------------------------------
__global__ __launch_bounds__(256) void wpose_kernel(
    const float* __restrict__ w, unsigned short* __restrict__ wT)
{
    __shared__ __align__(16) unsigned short Ls[64][68];
    const int d0 = blockIdx.x * 64;
    const int nh = blockIdx.y;        // 0..47
    const int tid = threadIdx.x;

    const float* wb = w + (size_t)nh * D_ * DH_ + (size_t)d0 * DH_;
    #pragma unroll
    for (int p = 0; p < 4; p++) {
        int i4  = tid + p * 256;
        int row = i4 >> 4;            // d
        int c4  = (i4 & 15) << 2;     // dh
        float4 v = *(const float4*)(wb + (size_t)row * DH_ + c4);
        uint2 u;
        u.x = cvt_pk_bf16(v.x, v.y);
        u.y = cvt_pk_bf16(v.z, v.w);
        *(uint2*)&Ls[row][c4] = u;
    }
    __syncthreads();
    unsigned short* ob = wT + (size_t)nh * DH_ * D_ + d0;
    #pragma unroll
    for (int p = 0; p < 2; p++) {
        int i    = tid + p * 256;
        int orow = i >> 3;            // dh
        int oc8  = (i & 7) * 8;       // d
        u16x8 tv;
        #pragma unroll
        for (int j = 0; j < 8; j++) tv[j] = Ls[oc8 + j][orow];
        *(u16x8*)(ob + (size_t)orow * D_ + oc8) = tv;
    }
}

// ---------------------------------------------------------------------------
// Kernel G: QKV projection, ROUND-9: true m97 structure + T2 swizzle.
// R8 post-mortem: linear [128][64] tile = 16-way bank conflict on every
// fragment read (G4), and 64 KB dbuf halved occupancy — gains canceled.
// Fix: single 32 KB buffer (2 barriers/iter, m97's actual shape), LDS block
// = Es = 34816 B -> (256,3) = 12 waves/CU; and rule-21 both-sides swizzle:
// gload_lds writes LINEAR LDS, global SOURCE chunk pre-XORed by row (lane&7
// ^ lane>>3), fragment READS XOR by (c15&7) — the attn kernel's proven
// formula family.  Frag reads: 16-way -> 2-way (free).
// q pre-scale folds 1/sqrt(Dh) AND log2(e): attn computes p = exp2(s).
// ---------------------------------------------------------------------------
__global__ __launch_bounds__(256, 3) void proj_mfma_kernel(
    const unsigned short* __restrict__ xT, const unsigned short* __restrict__ wT,
    unsigned short* __restrict__ qk, unsigned short* __restrict__ vT)
{
    // shorts: Xs[128][64] = [0,8192)  Ws[128][64] = [8192,16384)
    //         Es[128][136] = [0,17408) (epilogue, post-barrier reuse)
    __shared__ __align__(16) unsigned short Buf[17408];   // 34816 B
    unsigned short* Xs = Buf;
    unsigned short* Ws = Buf + 8192;
    unsigned short* Es = Buf;

    const int t0 = blockIdx.x * 128;
    const int y  = blockIdx.y;        // n*16 + b*8 + hp
    const int n  = y >> 4;
    const int b  = (y >> 3) & 1;
    const int hp = y & 7;             // head pair: heads 2hp, 2hp+1

    const unsigned short* xb = xT + (size_t)b * T_ * D_ + (size_t)t0 * D_;
    const unsigned short* wb = wT + (size_t)(n * 16 + 2 * hp) * DH_ * D_;

    const int tid  = threadIdx.x;
    const int wv   = tid >> 6;
    const int lane = tid & 63;
    const int c15  = lane & 15;
    const int quad = lane >> 4;
    const int tq   = (wv & 1) * 64;   // wave's t base
    const int dq   = (wv >> 1) * 64;  // wave's dh base

    // staging: wave owns rows [wv*32, wv*32+32); 4 insts x 8 rows per matrix.
    // gload_lds writes LDS linearly (base + lane*16); the SOURCE chunk is
    // pre-swizzled so LDS[r][c] holds global chunk c ^ (r&7)  (rule 21).
    const int srow8 = lane >> 3;              // 0..7 (row within 8-row group)
    const int ssw   = ((lane & 7) ^ srow8) * 8;   // swizzled src chunk (shorts)
    const int h7c   = c15 & 7;                // read-side swizzle key

    f32x4 acc[4][4];
    #pragma unroll
    for (int mt = 0; mt < 4; mt++)
        #pragma unroll
        for (int nt = 0; nt < 4; nt++)
            acc[mt][nt] = (f32x4){0.f, 0.f, 0.f, 0.f};

    for (int k0 = 0; k0 < D_; k0 += 64) {
        __syncthreads();   // previous compute done reading Xs/Ws
        #pragma unroll
        for (int i = 0; i < 4; i++) {
            int row0 = wv * 32 + i * 8;           // wave-uniform LDS row base
            gload_lds16(xb + (size_t)(row0 + srow8) * D_ + k0 + ssw, Xs + row0 * 64);
            gload_lds16(wb + (size_t)(row0 + srow8) * D_ + k0 + ssw, Ws + row0 * 64);
        }
        __syncthreads();   // barrier drains vmcnt -> tile resident

        bf16x8 af[4][2], bf[4][2];
        #pragma unroll
        for (int mt = 0; mt < 4; mt++)
            #pragma unroll
            for (int s = 0; s < 2; s++)
                af[mt][s] = *(bf16x8*)&Xs[(tq + mt * 16 + c15) * 64 +
                                          (((quad + 4 * s) ^ h7c) * 8)];
        #pragma unroll
        for (int nt = 0; nt < 4; nt++)
            #pragma unroll
            for (int s = 0; s < 2; s++)
                bf[nt][s] = *(bf16x8*)&Ws[(dq + nt * 16 + c15) * 64 +
                                          (((quad + 4 * s) ^ h7c) * 8)];

        #pragma unroll
        for (int mt = 0; mt < 4; mt++)
            #pragma unroll
            for (int nt = 0; nt < 4; nt++)
                #pragma unroll
                for (int s = 0; s < 2; s++)
                    acc[mt][nt] = __builtin_amdgcn_mfma_f32_16x16x32_bf16(
                        af[mt][s], bf[nt][s], acc[mt][nt], 0, 0, 0);
    }

    // q scale folds 1/sqrt(Dh) AND log2(e): attn computes p = exp2(s)
    const float scale = (n == 0) ? 0.125f * 1.44269504f : 1.0f;
    __syncthreads();   // all waves done reading tiles before Es overwrite
    #pragma unroll
    for (int mt = 0; mt < 4; mt++)
        #pragma unroll
        for (int nt = 0; nt < 4; nt++)
            #pragma unroll
            for (int r = 0; r < 4; r++) {
                float v = acc[mt][nt][r] * scale;
                Es[(tq + mt * 16 + quad * 4 + r) * 136 + dq + nt * 16 + c15] =
                    (unsigned short)cvt_pk_bf16(v, v);
            }
    __syncthreads();

    if (n < 2) {
        #pragma unroll
        for (int p = 0; p < 8; p++) {
            int i    = tid + p * 256;
            int row  = i >> 4;            // t 0..127
            int col8 = (i & 15) * 8;      // dh 0..120
            int head = col8 >> 6;
            unsigned short* ob = qk +
                ((size_t)(n * 32 + b * 16 + 2 * hp + head) * T_ + t0 + row) * DH_ + (col8 & 63);
            *(u16x8*)ob = *(u16x8*)&Es[row * 136 + col8];
        }
    } else {
        // v: transposed read-out -> vT[bh][dh][t]
        #pragma unroll
        for (int p = 0; p < 8; p++) {
            int i    = tid + p * 256;
            int orow = i >> 4;            // dh 0..127
            int oc8  = (i & 15) * 8;      // t 0..120
            int head = orow >> 6;
            u16x8 tv;
            #pragma unroll
            for (int j = 0; j < 8; j++) tv[j] = Es[(oc8 + j) * 136 + orow];
            unsigned short* ob = vT +
                (size_t)(b * 16 + 2 * hp + head) * DH_ * T_ +
                (size_t)(orow & 63) * T_ + t0 + oc8;
            *(u16x8*)ob = tv;
        }
    }
}

// ---------------------------------------------------------------------------
// Kernel A: flash attention — EXACT ROUND-1 KERNEL (61.4 us proven, VGPR 52).
// 256 thr, 4 waves x 16 q, K/V LDS-staged double-buffered XOR-swizzled,
// per-wave P, 1 barrier/iter, fixed-max softmax with exp2 (log2e folded
// into q) + cvt_pk packing.  DO NOT MODIFY without a verified theory:
// fat-q (r7) failed correctness; V-direct (r2/r5/r6) failed perf.
// ---------------------------------------------------------------------------
__global__ __launch_bounds__(256, 4) void attn_mfma_kernel(
    const unsigned short* __restrict__ qk, const unsigned short* __restrict__ vT,
    float* __restrict__ out)
{
    // shorts: K0[0,4096) V0[4096,8192) K1[8192,12288) V1[12288,16384)
    //         P 4 x [16][64] at [16384,20480).  Total 40960 B.
    __shared__ __align__(16) unsigned short Sm[20480];

    const int flat = blockIdx.x;                            // 0..1023
    const int bh   = (flat & 7) * 4 + ((flat >> 3) >> 5);   // XCD swizzle: 4 bh/XCD
    const int t0   = ((flat >> 3) & 31) * 64;

    const unsigned short* qg = qk + ((size_t)bh * T_ + t0) * DH_;   // pre-scaled q
    const unsigned short* kg = qk + ((size_t)(BH_ + bh) * T_) * DH_;
    const unsigned short* vg = vT + (size_t)bh * DH_ * T_;          // [dh][t]

    const int tid  = threadIdx.x;
    const int wv   = tid >> 6;
    const int lane = tid & 63;
    const int c15  = lane & 15;
    const int quad = lane >> 4;
    const int swz  = (c15 & 7) * 8;   // P-column swizzle (shorts)
    const int h7   = c15 & 7;         // K/V chunk swizzle key

    unsigned short* Ps = Sm + 16384 + wv * 1024;   // [16][64]

    const int srow = tid >> 3;        // staging row 0..31
    const int sch  = tid & 7;         // staging logical chunk 0..7
    const int ssw  = ((sch ^ (srow & 7)) * 8);   // swizzled short offset in row

    // Q^T B-fragments straight from global: wave owns q rows wv*16..+16
    bf16x8 bq[2];
    #pragma unroll
    for (int s = 0; s < 2; s++)
        bq[s] = *(const bf16x8*)(qg + (size_t)(wv * 16 + c15) * DH_ + quad * 8 + s * 32);

    float lsum = 0.f;
    f32x4 Oacc[4];
    #pragma unroll
    for (int nt = 0; nt < 4; nt++) Oacc[nt] = (f32x4){0.f, 0.f, 0.f, 0.f};

    // preload tile 0 and stage into buffer 0 (no prior readers)
    u16x8 kreg[2], vreg[2];
    #pragma unroll
    for (int p = 0; p < 2; p++) {
        int row = srow + p * 32;
        kreg[p] = *(const u16x8*)(kg + (size_t)row * DH_ + sch * 8);
        vreg[p] = *(const u16x8*)(vg + (size_t)row * T_ + sch * 8);
    }
    #pragma unroll
    for (int p = 0; p < 2; p++) {
        int row = srow + p * 32;
        *(u16x8*)&Sm[row * 64 + ssw]        = kreg[p];
        *(u16x8*)&Sm[4096 + row * 64 + ssw] = vreg[p];
    }

    for (int tau = 0; tau < T_; tau += 64) {
        const int cur = (tau >> 6) & 1;
        unsigned short* Ks = Sm + cur * 8192;
        unsigned short* Vs = Ks + 4096;
        __syncthreads();   // tile tau staged by all waves; buf[1-cur] free

        const bool pf = (tau + 64 < T_);
        if (pf) {   // issue global loads for tile tau+1 early
            #pragma unroll
            for (int p = 0; p < 2; p++) {
                int row = srow + p * 32;
                kreg[p] = *(const u16x8*)(kg + (size_t)(tau + 64 + row) * DH_ + sch * 8);
                vreg[p] = *(const u16x8*)(vg + (size_t)row * T_ + tau + 64 + sch * 8);
            }
        }

        // S^T = K Q^T per 16-key block; exp2; swizzled b64 write to own-wave Ps
        #pragma unroll
        for (int mt = 0; mt < 4; mt++) {
            f32x4 sa = (f32x4){0.f, 0.f, 0.f, 0.f};
            #pragma unroll
            for (int s = 0; s < 2; s++) {
                bf16x8 ak = *(bf16x8*)&Ks[(mt * 16 + c15) * 64 +
                                          (((quad + 4 * s) ^ h7) * 8)];
                sa = __builtin_amdgcn_mfma_f32_16x16x32_bf16(ak, bq[s], sa, 0, 0, 0);
            }
            float p0 = __builtin_amdgcn_exp2f(sa[0]);
            float p1 = __builtin_amdgcn_exp2f(sa[1]);
            float p2 = __builtin_amdgcn_exp2f(sa[2]);
            float p3 = __builtin_amdgcn_exp2f(sa[3]);
            lsum += (p0 + p1) + (p2 + p3);
            uint2 pk;
            pk.x = cvt_pk_bf16(p0, p1);
            pk.y = cvt_pk_bf16(p2, p3);
            *(uint2*)&Ps[c15 * 64 + ((mt * 16 + quad * 4) ^ swz)] = pk;
        }
        // no barrier: Ps per-wave, same-wave DS ordering

        // O += P V : A = P rows (swizzled b128), B = V^T fragments (swizzled)
        #pragma unroll
        for (int s = 0; s < 2; s++) {
            bf16x8 ap = *(bf16x8*)&Ps[c15 * 64 + ((quad * 8 + s * 32) ^ swz)];
            #pragma unroll
            for (int nt = 0; nt < 4; nt++) {
                bf16x8 bv = *(bf16x8*)&Vs[(nt * 16 + c15) * 64 +
                                          (((quad + 4 * s) ^ h7) * 8)];
                Oacc[nt] = __builtin_amdgcn_mfma_f32_16x16x32_bf16(ap, bv, Oacc[nt], 0, 0, 0);
            }
        }

        if (pf) {   // stage tile tau+1 into the alternate buffer
            unsigned short* Kn = Sm + (1 - cur) * 8192;
            #pragma unroll
            for (int p = 0; p < 2; p++) {
                int row = srow + p * 32;
                *(u16x8*)&Kn[row * 64 + ssw]        = kreg[p];
                *(u16x8*)&Kn[4096 + row * 64 + ssw] = vreg[p];
            }
        }
    }

    // row sums: reduce across quads; linv via shfl
    lsum += __shfl_xor(lsum, 16);
    lsum += __shfl_xor(lsum, 32);
    float linv[4];
    #pragma unroll
    for (int r = 0; r < 4; r++)
        linv[r] = 1.0f / __shfl(lsum, quad * 4 + r);

    // epilogue: per-wave transpose through LDS ([64][17] f32 per wave)
    __syncthreads();   // all waves done with K/V/P reads
    float* Osw = (float*)(void*)Sm + wv * 1088;
    #pragma unroll
    for (int nt = 0; nt < 4; nt++)
        #pragma unroll
        for (int r = 0; r < 4; r++)
            Osw[(nt * 16 + c15) * 17 + quad * 4 + r] = Oacc[nt][r] * linv[r];

    const int b = bh >> 4, h = bh & 15;
    float* og = out + (size_t)b * D_ * T_ + (size_t)(h * DH_) * T_ + t0 + wv * 16;
    #pragma unroll
    for (int p = 0; p < 4; p++) {
        int idx = lane + p * 64;
        int dh  = idx >> 2;          // 0..63
        int qs  = (idx & 3) * 4;     // 0,4,8,12
        float4 v = *(float4*)&Osw[dh * 17 + qs];
        *(float4*)(og + (size_t)dh * T_ + qs) = v;
    }
}

extern "C" void kernel_launch(void* const* d_in, const int* in_sizes, int n_in,
                              void* d_out, int out_size, void* d_ws, size_t ws_size,
                              hipStream_t stream)
{
    const float* x = (const float*)d_in[0];   // (B, D, T) fp32
    const float* w = (const float*)d_in[1];   // (3, H, D, Dh) fp32
    float* out = (float*)d_out;               // (B, D, T) fp32

    // ws layout:
    unsigned short* qk = (unsigned short*)d_ws;                           // [2][32][T][64] bf16 = 16 MB (+8 MB slack)
    unsigned short* vT = (unsigned short*)((char*)d_ws + (24u << 20));    // [32][64][T] bf16 = 8 MB
    unsigned short* xT = (unsigned short*)((char*)d_ws + (32u << 20));    // [B][T][D] bf16 = 8 MB
    unsigned short* wT = (unsigned short*)((char*)d_ws + (40u << 20));    // [3][H][64][D] bf16 = 6 MB

    xpose_kernel<<<dim3(T_ / 64, D_ / 64, B_), 256, 0, stream>>>(x, xT);
    wpose_kernel<<<dim3(D_ / 64, 3 * H_), 256, 0, stream>>>(w, wT);
    proj_mfma_kernel<<<dim3(T_ / 128, 48), 256, 0, stream>>>(xT, wT, qk, vT);
    attn_mfma_kernel<<<1024, 256, 0, stream>>>(qk, vT, out);
}

// Round 10
// 167.196 us; speedup vs baseline: 1.0130x; 1.0130x over previous
//
#include <hip/hip_runtime.h>

#define B_ 2
#define D_ 1024
#define T_ 2048
#define H_ 16
#define DH_ 64
#define BH_ (B_ * H_)

typedef __attribute__((ext_vector_type(8))) short bf16x8;
typedef __attribute__((ext_vector_type(8))) unsigned short u16x8;
typedef __attribute__((ext_vector_type(4))) float f32x4;

// two f32 -> packed 2x bf16 (RNE) in ONE VALU op (no builtin on gfx950; T12 recipe)
__device__ __forceinline__ unsigned cvt_pk_bf16(float a, float b) {
    unsigned r;
    asm("v_cvt_pk_bf16_f32 %0, %1, %2" : "=v"(r) : "v"(a), "v"(b));
    return r;
}

// async global->LDS, 16 B per lane: LDS dest is wave-uniform base + lane*16,
// global src is per-lane.  (m97 pattern; size must be a literal.)
__device__ __forceinline__ void gload_lds16(const unsigned short* g, unsigned short* l) {
    __builtin_amdgcn_global_load_lds(
        (const __attribute__((address_space(1))) unsigned int*)(const void*)g,
        (__attribute__((address_space(3))) unsigned int*)(void*)l,
        16, 0, 0);
}

// ---------------------------------------------------------------------------
// Kernel T (fused): both input transposes in ONE launch (they are
// independent; previously serialized with a full drain between them).
// blocks [0,1024): x (B,D,T) fp32 -> xT (B,T,D) bf16, 64x64 tiles.
// blocks [1024,1792): w (3,H,D,Dh) fp32 -> wT (3,H,Dh,D) bf16.
// ---------------------------------------------------------------------------
__global__ __launch_bounds__(256) void pose_kernel(
    const float* __restrict__ x, const float* __restrict__ w,
    unsigned short* __restrict__ xT, unsigned short* __restrict__ wT)
{
    __shared__ __align__(16) unsigned short Ls[64][68];
    const int tid  = threadIdx.x;
    const int flat = blockIdx.x;

    if (flat < 1024) {
        const int t0 = (flat & 31) * 64;
        const int d0 = ((flat >> 5) & 15) * 64;
        const int b  = flat >> 9;

        const float* xb = x + (size_t)b * D_ * T_ + (size_t)d0 * T_ + t0;
        #pragma unroll
        for (int p = 0; p < 4; p++) {
            int i4  = tid + p * 256;
            int row = i4 >> 4;            // d
            int c4  = (i4 & 15) << 2;     // t
            float4 v = *(const float4*)(xb + (size_t)row * T_ + c4);
            uint2 u;
            u.x = cvt_pk_bf16(v.x, v.y);
            u.y = cvt_pk_bf16(v.z, v.w);
            *(uint2*)&Ls[row][c4] = u;
        }
        __syncthreads();
        unsigned short* ob = xT + (size_t)b * T_ * D_ + (size_t)t0 * D_ + d0;
        #pragma unroll
        for (int p = 0; p < 2; p++) {
            int i    = tid + p * 256;
            int orow = i >> 3;            // t
            int oc8  = (i & 7) * 8;       // d
            u16x8 tv;
            #pragma unroll
            for (int j = 0; j < 8; j++) tv[j] = Ls[oc8 + j][orow];
            *(u16x8*)(ob + (size_t)orow * D_ + oc8) = tv;
        }
    } else {
        const int f  = flat - 1024;
        const int d0 = (f & 15) * 64;
        const int nh = f >> 4;            // 0..47

        const float* wb = w + (size_t)nh * D_ * DH_ + (size_t)d0 * DH_;
        #pragma unroll
        for (int p = 0; p < 4; p++) {
            int i4  = tid + p * 256;
            int row = i4 >> 4;            // d
            int c4  = (i4 & 15) << 2;     // dh
            float4 v = *(const float4*)(wb + (size_t)row * DH_ + c4);
            uint2 u;
            u.x = cvt_pk_bf16(v.x, v.y);
            u.y = cvt_pk_bf16(v.z, v.w);
            *(uint2*)&Ls[row][c4] = u;
        }
        __syncthreads();
        unsigned short* ob = wT + (size_t)nh * DH_ * D_ + d0;
        #pragma unroll
        for (int p = 0; p < 2; p++) {
            int i    = tid + p * 256;
            int orow = i >> 3;            // dh
            int oc8  = (i & 7) * 8;       // d
            u16x8 tv;
            #pragma unroll
            for (int j = 0; j < 8; j++) tv[j] = Ls[oc8 + j][orow];
            *(u16x8*)(ob + (size_t)orow * D_ + oc8) = tv;
        }
    }
}

// ---------------------------------------------------------------------------
// Kernel G: QKV projection — ROUND-9 VERSION KEPT (passed; perf equal to the
// r1 pad-80 variant across three A/B rounds; async gload_lds staging).
// q pre-scale folds 1/sqrt(Dh) AND log2(e): attn computes p = exp2(s).
// ---------------------------------------------------------------------------
__global__ __launch_bounds__(256, 3) void proj_mfma_kernel(
    const unsigned short* __restrict__ xT, const unsigned short* __restrict__ wT,
    unsigned short* __restrict__ qk, unsigned short* __restrict__ vT)
{
    // shorts: Xs[128][64] = [0,8192)  Ws[128][64] = [8192,16384)
    //         Es[128][136] = [0,17408) (epilogue, post-barrier reuse)
    __shared__ __align__(16) unsigned short Buf[17408];   // 34816 B
    unsigned short* Xs = Buf;
    unsigned short* Ws = Buf + 8192;
    unsigned short* Es = Buf;

    const int t0 = blockIdx.x * 128;
    const int y  = blockIdx.y;        // n*16 + b*8 + hp
    const int n  = y >> 4;
    const int b  = (y >> 3) & 1;
    const int hp = y & 7;             // head pair: heads 2hp, 2hp+1

    const unsigned short* xb = xT + (size_t)b * T_ * D_ + (size_t)t0 * D_;
    const unsigned short* wb = wT + (size_t)(n * 16 + 2 * hp) * DH_ * D_;

    const int tid  = threadIdx.x;
    const int wv   = tid >> 6;
    const int lane = tid & 63;
    const int c15  = lane & 15;
    const int quad = lane >> 4;
    const int tq   = (wv & 1) * 64;   // wave's t base
    const int dq   = (wv >> 1) * 64;  // wave's dh base

    const int srow8 = lane >> 3;              // 0..7 (row within 8-row group)
    const int ssw   = ((lane & 7) ^ srow8) * 8;   // swizzled src chunk (shorts)
    const int h7c   = c15 & 7;                // read-side swizzle key

    f32x4 acc[4][4];
    #pragma unroll
    for (int mt = 0; mt < 4; mt++)
        #pragma unroll
        for (int nt = 0; nt < 4; nt++)
            acc[mt][nt] = (f32x4){0.f, 0.f, 0.f, 0.f};

    for (int k0 = 0; k0 < D_; k0 += 64) {
        __syncthreads();   // previous compute done reading Xs/Ws
        #pragma unroll
        for (int i = 0; i < 4; i++) {
            int row0 = wv * 32 + i * 8;           // wave-uniform LDS row base
            gload_lds16(xb + (size_t)(row0 + srow8) * D_ + k0 + ssw, Xs + row0 * 64);
            gload_lds16(wb + (size_t)(row0 + srow8) * D_ + k0 + ssw, Ws + row0 * 64);
        }
        __syncthreads();   // barrier drains vmcnt -> tile resident

        bf16x8 af[4][2], bf[4][2];
        #pragma unroll
        for (int mt = 0; mt < 4; mt++)
            #pragma unroll
            for (int s = 0; s < 2; s++)
                af[mt][s] = *(bf16x8*)&Xs[(tq + mt * 16 + c15) * 64 +
                                          (((quad + 4 * s) ^ h7c) * 8)];
        #pragma unroll
        for (int nt = 0; nt < 4; nt++)
            #pragma unroll
            for (int s = 0; s < 2; s++)
                bf[nt][s] = *(bf16x8*)&Ws[(dq + nt * 16 + c15) * 64 +
                                          (((quad + 4 * s) ^ h7c) * 8)];

        #pragma unroll
        for (int mt = 0; mt < 4; mt++)
            #pragma unroll
            for (int nt = 0; nt < 4; nt++)
                #pragma unroll
                for (int s = 0; s < 2; s++)
                    acc[mt][nt] = __builtin_amdgcn_mfma_f32_16x16x32_bf16(
                        af[mt][s], bf[nt][s], acc[mt][nt], 0, 0, 0);
    }

    // q scale folds 1/sqrt(Dh) AND log2(e): attn computes p = exp2(s)
    const float scale = (n == 0) ? 0.125f * 1.44269504f : 1.0f;
    __syncthreads();   // all waves done reading tiles before Es overwrite
    #pragma unroll
    for (int mt = 0; mt < 4; mt++)
        #pragma unroll
        for (int nt = 0; nt < 4; nt++)
            #pragma unroll
            for (int r = 0; r < 4; r++) {
                float v = acc[mt][nt][r] * scale;
                Es[(tq + mt * 16 + quad * 4 + r) * 136 + dq + nt * 16 + c15] =
                    (unsigned short)cvt_pk_bf16(v, v);
            }
    __syncthreads();

    if (n < 2) {
        #pragma unroll
        for (int p = 0; p < 8; p++) {
            int i    = tid + p * 256;
            int row  = i >> 4;            // t 0..127
            int col8 = (i & 15) * 8;      // dh 0..120
            int head = col8 >> 6;
            unsigned short* ob = qk +
                ((size_t)(n * 32 + b * 16 + 2 * hp + head) * T_ + t0 + row) * DH_ + (col8 & 63);
            *(u16x8*)ob = *(u16x8*)&Es[row * 136 + col8];
        }
    } else {
        // v: transposed read-out -> vT[bh][dh][t]
        #pragma unroll
        for (int p = 0; p < 8; p++) {
            int i    = tid + p * 256;
            int orow = i >> 4;            // dh 0..127
            int oc8  = (i & 15) * 8;      // t 0..120
            int head = orow >> 6;
            u16x8 tv;
            #pragma unroll
            for (int j = 0; j < 8; j++) tv[j] = Es[(oc8 + j) * 136 + orow];
            unsigned short* ob = vT +
                (size_t)(b * 16 + 2 * hp + head) * DH_ * T_ +
                (size_t)(orow & 63) * T_ + t0 + oc8;
            *(u16x8*)ob = tv;
        }
    }
}

// ---------------------------------------------------------------------------
// Kernel A: flash attention — round-1 proven kernel (61.4 us, VGPR 52)
// + T5 s_setprio(1) wrapped tightly around the MFMA clusters (m191: +4-7%
// on attn-class structures; pure scheduler hint, no semantic change).
// Otherwise byte-identical: 256 thr, 4 waves x 16 q, K/V LDS-staged
// double-buffered XOR-swizzled, per-wave P, 1 barrier/iter, fixed-max
// softmax with exp2 (log2e folded into q) + cvt_pk packing.
// ---------------------------------------------------------------------------
__global__ __launch_bounds__(256, 4) void attn_mfma_kernel(
    const unsigned short* __restrict__ qk, const unsigned short* __restrict__ vT,
    float* __restrict__ out)
{
    // shorts: K0[0,4096) V0[4096,8192) K1[8192,12288) V1[12288,16384)
    //         P 4 x [16][64] at [16384,20480).  Total 40960 B.
    __shared__ __align__(16) unsigned short Sm[20480];

    const int flat = blockIdx.x;                            // 0..1023
    const int bh   = (flat & 7) * 4 + ((flat >> 3) >> 5);   // XCD swizzle: 4 bh/XCD
    const int t0   = ((flat >> 3) & 31) * 64;

    const unsigned short* qg = qk + ((size_t)bh * T_ + t0) * DH_;   // pre-scaled q
    const unsigned short* kg = qk + ((size_t)(BH_ + bh) * T_) * DH_;
    const unsigned short* vg = vT + (size_t)bh * DH_ * T_;          // [dh][t]

    const int tid  = threadIdx.x;
    const int wv   = tid >> 6;
    const int lane = tid & 63;
    const int c15  = lane & 15;
    const int quad = lane >> 4;
    const int swz  = (c15 & 7) * 8;   // P-column swizzle (shorts)
    const int h7   = c15 & 7;         // K/V chunk swizzle key

    unsigned short* Ps = Sm + 16384 + wv * 1024;   // [16][64]

    const int srow = tid >> 3;        // staging row 0..31
    const int sch  = tid & 7;         // staging logical chunk 0..7
    const int ssw  = ((sch ^ (srow & 7)) * 8);   // swizzled short offset in row

    // Q^T B-fragments straight from global: wave owns q rows wv*16..+16
    bf16x8 bq[2];
    #pragma unroll
    for (int s = 0; s < 2; s++)
        bq[s] = *(const bf16x8*)(qg + (size_t)(wv * 16 + c15) * DH_ + quad * 8 + s * 32);

    float lsum = 0.f;
    f32x4 Oacc[4];
    #pragma unroll
    for (int nt = 0; nt < 4; nt++) Oacc[nt] = (f32x4){0.f, 0.f, 0.f, 0.f};

    // preload tile 0 and stage into buffer 0 (no prior readers)
    u16x8 kreg[2], vreg[2];
    #pragma unroll
    for (int p = 0; p < 2; p++) {
        int row = srow + p * 32;
        kreg[p] = *(const u16x8*)(kg + (size_t)row * DH_ + sch * 8);
        vreg[p] = *(const u16x8*)(vg + (size_t)row * T_ + sch * 8);
    }
    #pragma unroll
    for (int p = 0; p < 2; p++) {
        int row = srow + p * 32;
        *(u16x8*)&Sm[row * 64 + ssw]        = kreg[p];
        *(u16x8*)&Sm[4096 + row * 64 + ssw] = vreg[p];
    }

    for (int tau = 0; tau < T_; tau += 64) {
        const int cur = (tau >> 6) & 1;
        unsigned short* Ks = Sm + cur * 8192;
        unsigned short* Vs = Ks + 4096;
        __syncthreads();   // tile tau staged by all waves; buf[1-cur] free

        const bool pf = (tau + 64 < T_);
        if (pf) {   // issue global loads for tile tau+1 early
            #pragma unroll
            for (int p = 0; p < 2; p++) {
                int row = srow + p * 32;
                kreg[p] = *(const u16x8*)(kg + (size_t)(tau + 64 + row) * DH_ + sch * 8);
                vreg[p] = *(const u16x8*)(vg + (size_t)row * T_ + tau + 64 + sch * 8);
            }
        }

        // S^T = K Q^T per 16-key block; exp2; swizzled b64 write to own-wave Ps
        #pragma unroll
        for (int mt = 0; mt < 4; mt++) {
            bf16x8 ak0 = *(bf16x8*)&Ks[(mt * 16 + c15) * 64 + ((quad ^ h7) * 8)];
            bf16x8 ak1 = *(bf16x8*)&Ks[(mt * 16 + c15) * 64 + (((quad + 4) ^ h7) * 8)];
            f32x4 sa = (f32x4){0.f, 0.f, 0.f, 0.f};
            __builtin_amdgcn_s_setprio(1);
            sa = __builtin_amdgcn_mfma_f32_16x16x32_bf16(ak0, bq[0], sa, 0, 0, 0);
            sa = __builtin_amdgcn_mfma_f32_16x16x32_bf16(ak1, bq[1], sa, 0, 0, 0);
            __builtin_amdgcn_s_setprio(0);
            float p0 = __builtin_amdgcn_exp2f(sa[0]);
            float p1 = __builtin_amdgcn_exp2f(sa[1]);
            float p2 = __builtin_amdgcn_exp2f(sa[2]);
            float p3 = __builtin_amdgcn_exp2f(sa[3]);
            lsum += (p0 + p1) + (p2 + p3);
            uint2 pk;
            pk.x = cvt_pk_bf16(p0, p1);
            pk.y = cvt_pk_bf16(p2, p3);
            *(uint2*)&Ps[c15 * 64 + ((mt * 16 + quad * 4) ^ swz)] = pk;
        }
        // no barrier: Ps per-wave, same-wave DS ordering

        // O += P V : A = P rows (swizzled b128), B = V^T fragments (swizzled)
        #pragma unroll
        for (int s = 0; s < 2; s++) {
            bf16x8 ap = *(bf16x8*)&Ps[c15 * 64 + ((quad * 8 + s * 32) ^ swz)];
            bf16x8 bv[4];
            #pragma unroll
            for (int nt = 0; nt < 4; nt++)
                bv[nt] = *(bf16x8*)&Vs[(nt * 16 + c15) * 64 +
                                       (((quad + 4 * s) ^ h7) * 8)];
            __builtin_amdgcn_s_setprio(1);
            #pragma unroll
            for (int nt = 0; nt < 4; nt++)
                Oacc[nt] = __builtin_amdgcn_mfma_f32_16x16x32_bf16(ap, bv[nt], Oacc[nt], 0, 0, 0);
            __builtin_amdgcn_s_setprio(0);
        }

        if (pf) {   // stage tile tau+1 into the alternate buffer
            unsigned short* Kn = Sm + (1 - cur) * 8192;
            #pragma unroll
            for (int p = 0; p < 2; p++) {
                int row = srow + p * 32;
                *(u16x8*)&Kn[row * 64 + ssw]        = kreg[p];
                *(u16x8*)&Kn[4096 + row * 64 + ssw] = vreg[p];
            }
        }
    }

    // row sums: reduce across quads; linv via shfl
    lsum += __shfl_xor(lsum, 16);
    lsum += __shfl_xor(lsum, 32);
    float linv[4];
    #pragma unroll
    for (int r = 0; r < 4; r++)
        linv[r] = 1.0f / __shfl(lsum, quad * 4 + r);

    // epilogue: per-wave transpose through LDS ([64][17] f32 per wave)
    __syncthreads();   // all waves done with K/V/P reads
    float* Osw = (float*)(void*)Sm + wv * 1088;
    #pragma unroll
    for (int nt = 0; nt < 4; nt++)
        #pragma unroll
        for (int r = 0; r < 4; r++)
            Osw[(nt * 16 + c15) * 17 + quad * 4 + r] = Oacc[nt][r] * linv[r];

    const int b = bh >> 4, h = bh & 15;
    float* og = out + (size_t)b * D_ * T_ + (size_t)(h * DH_) * T_ + t0 + wv * 16;
    #pragma unroll
    for (int p = 0; p < 4; p++) {
        int idx = lane + p * 64;
        int dh  = idx >> 2;          // 0..63
        int qs  = (idx & 3) * 4;     // 0,4,8,12
        float4 v = *(float4*)&Osw[dh * 17 + qs];
        *(float4*)(og + (size_t)dh * T_ + qs) = v;
    }
}

extern "C" void kernel_launch(void* const* d_in, const int* in_sizes, int n_in,
                              void* d_out, int out_size, void* d_ws, size_t ws_size,
                              hipStream_t stream)
{
    const float* x = (const float*)d_in[0];   // (B, D, T) fp32
    const float* w = (const float*)d_in[1];   // (3, H, D, Dh) fp32
    float* out = (float*)d_out;               // (B, D, T) fp32

    // ws layout:
    unsigned short* qk = (unsigned short*)d_ws;                           // [2][32][T][64] bf16 = 16 MB (+8 MB slack)
    unsigned short* vT = (unsigned short*)((char*)d_ws + (24u << 20));    // [32][64][T] bf16 = 8 MB
    unsigned short* xT = (unsigned short*)((char*)d_ws + (32u << 20));    // [B][T][D] bf16 = 8 MB
    unsigned short* wT = (unsigned short*)((char*)d_ws + (40u << 20));    // [3][H][64][D] bf16 = 6 MB

    pose_kernel<<<1792, 256, 0, stream>>>(x, w, xT, wT);
    proj_mfma_kernel<<<dim3(T_ / 128, 48), 256, 0, stream>>>(xT, wT, qk, vT);
    attn_mfma_kernel<<<1024, 256, 0, stream>>>(qk, vT, out);
}